// Round 3
// baseline (78.815 us; speedup 1.0000x reference)
//
#include <hip/hip_runtime.h>
#include <stdint.h>

#define N 384
#define D 1024
#define N2 (N * N)            // 147456
static constexpr size_t N3 = (size_t)N * N2;  // 56623104

// ---- workspace byte offsets (total ~1.2 MB) ----
static constexpr size_t MAT_OFF = 0;              // 147456*8 = 1179648
static constexpr size_t TN_OFF  = 1179648;        // 384 doubles
static constexpr size_t TC_OFF  = 1182720;
static constexpr size_t ANS_OFF = 1185792;
static constexpr size_t ANC_OFF = 1188864;
static constexpr size_t HP_OFF  = 1191936;        // 384 ints
static constexpr size_t SC_OFF  = 1193472;        // 2 doubles (eps, beta)

// ---- scratch carved out of d_out (fully overwritten by k_cond later) ----
static constexpr size_t PART_BYTE = 0;            // 4*147456*8 = 4718592
static constexpr size_t XN_BYTE   = 8388608;      // 384*1024*8 = 3145728

// ---------------- K1: row L2-normalize in fp64 ---------------------------
__global__ __launch_bounds__(256) void k_norm(const float* __restrict__ x,
                                              double* __restrict__ xn) {
  __shared__ double red[256];
  int a = blockIdx.x;
  int t = threadIdx.x;
  float4 v = ((const float4*)(x + (size_t)a * D))[t];
  double dx = v.x, dy = v.y, dz = v.z, dw = v.w;
  red[t] = dx * dx + dy * dy + dz * dz + dw * dw;
  __syncthreads();
  for (int s = 128; s > 0; s >>= 1) {
    if (t < s) red[t] += red[t + s];
    __syncthreads();
  }
  double n = sqrt(red[0]);
  double* o = xn + (size_t)a * D + 4 * t;
  o[0] = dx / n; o[1] = dy / n; o[2] = dz / n; o[3] = dw / n;
}

// ---------------- K2: fp64 GEMM partials, K-split by 4 -------------------
// grid (12,12,4), block 256. Tile 32x32, K-chunk 256 per block (64 in LDS).
__global__ __launch_bounds__(256) void k_gemm(const double* __restrict__ xn,
                                              double* __restrict__ part) {
  __shared__ double As[64][32];
  __shared__ double Bs[64][32];
  int t = threadIdx.x;
  int m0 = blockIdx.x * 32, n0 = blockIdx.y * 32, k0 = blockIdx.z * 256;
  int tm = t & 15, tn = t >> 4;
  double a00 = 0, a01 = 0, a10 = 0, a11 = 0;
  for (int kc = 0; kc < 4; ++kc) {
    int kbase = k0 + kc * 64;
#pragma unroll
    for (int h = 0; h < 4; ++h) {
      int f = t + h * 256;          // 0..1023
      int m = f & 31, kq = f >> 5;  // kq 0..31
      double2 va = *(const double2*)(xn + (size_t)(m0 + m) * D + kbase + kq * 2);
      As[kq * 2][m] = va.x; As[kq * 2 + 1][m] = va.y;
      double2 vb = *(const double2*)(xn + (size_t)(n0 + m) * D + kbase + kq * 2);
      Bs[kq * 2][m] = vb.x; Bs[kq * 2 + 1][m] = vb.y;
    }
    __syncthreads();
#pragma unroll 8
    for (int k = 0; k < 64; ++k) {
      double ax = As[k][2 * tm], ay = As[k][2 * tm + 1];
      double bx = Bs[k][2 * tn], by = Bs[k][2 * tn + 1];
      a00 = fma(ax, bx, a00);
      a01 = fma(ax, by, a01);
      a10 = fma(ay, bx, a10);
      a11 = fma(ay, by, a11);
    }
    __syncthreads();
  }
  double* o = part + (size_t)blockIdx.z * N2;
  int r0 = m0 + 2 * tm, c0 = n0 + 2 * tn;
  o[(size_t)r0 * N + c0]           = a00;
  o[(size_t)r0 * N + c0 + 1]       = a01;
  o[(size_t)(r0 + 1) * N + c0]     = a10;
  o[(size_t)(r0 + 1) * N + c0 + 1] = a11;
}

// ---------------- K2r: fixed-order partial reduce, negate ----------------
__global__ __launch_bounds__(256) void k_reduce_mat(const double* __restrict__ part,
                                                    double* __restrict__ mat) {
  int i = blockIdx.x * 256 + threadIdx.x;   // grid 576 -> exactly N2
  double s = part[i];
  s += part[(size_t)N2 + i];
  s += part[2 * (size_t)N2 + i];
  s += part[3 * (size_t)N2 + i];
  mat[i] = -s;
}

// ---------------- K3: per-anchor stats (double, deterministic tree) ------
__global__ __launch_bounds__(384) void k_stats(const double* __restrict__ mat,
                                               const int* __restrict__ labels,
                                               double* __restrict__ tn,
                                               double* __restrict__ tc,
                                               double* __restrict__ ans,
                                               double* __restrict__ anc,
                                               int* __restrict__ hp) {
  __shared__ int labs[N];
  __shared__ int hist[32];
  __shared__ double red[512];
  int a = blockIdx.x, t = threadIdx.x;
  if (t < 32) hist[t] = 0;
  labs[t] = labels[t];
  __syncthreads();
  atomicAdd(&hist[labs[t] & 31], 1);
  __syncthreads();
  int la = labs[a];
  double m = mat[(size_t)a * N + t];
  bool same = (labs[t] == la) && (t != a);
  bool diff = (labs[t] != la);
  bool hpa = hist[la] >= 2;
  bool hpt = hist[labs[t]] >= 2;
  bool anm = (t > a) && diff && (hpa || hpt);

  auto reduceD = [&](double v) -> double {
    red[t] = v;
    if (t < 128) red[384 + t] = 0.0;
    __syncthreads();
    for (int s = 256; s > 0; s >>= 1) {
      if (t < s) red[t] += red[t + s];
      __syncthreads();
    }
    double r = red[0];
    __syncthreads();
    return r;
  };
  double sumS = reduceD(same ? m : 0.0);
  double cntS = reduceD(same ? 1.0 : 0.0);
  double sumD = reduceD(diff ? m : 0.0);
  double cntD = reduceD(diff ? 1.0 : 0.0);
  double sumA = reduceD(anm ? m : 0.0);
  double cntA = reduceD(anm ? 1.0 : 0.0);
  if (t == 0) {
    tn[a]  = sumD * cntS - sumS * cntD;
    tc[a]  = cntS * cntD;
    ans[a] = sumA;
    anc[a] = cntA;
    hp[a]  = hpa ? 1 : 0;
  }
}

// ---------------- K3c: final scalars eps/beta ----------------------------
__global__ __launch_bounds__(512) void k_final(const double* __restrict__ tn,
                                               const double* __restrict__ tc,
                                               const double* __restrict__ ans,
                                               const double* __restrict__ anc,
                                               double* __restrict__ sc,
                                               float* __restrict__ out_tail) {
  __shared__ double red[512];
  int t = threadIdx.x;
  auto reduceD = [&](double v) -> double {
    red[t] = v;
    __syncthreads();
    for (int s = 256; s > 0; s >>= 1) {
      if (t < s) red[t] += red[t + s];
      __syncthreads();
    }
    double r = red[0];
    __syncthreads();
    return r;
  };
  double Ttn = reduceD(t < N ? tn[t] : 0.0);
  double Ttc = reduceD(t < N ? tc[t] : 0.0);
  double Tas = reduceD(t < N ? ans[t] : 0.0);
  double Tac = reduceD(t < N ? anc[t] : 0.0);
  if (t == 0) {
    double an_mean = Tas / fmax(Tac, 1.0);
    double beta = 1.0 + ((-an_mean) - 1.0) / 2.0;
    double em = Ttn / fmax(Ttc, 1.0);
    double eps = em / 2.0;
    eps = eps < 0.0 ? 0.0 : (eps > 0.5 ? 0.5 : eps);
    sc[0] = eps;
    sc[1] = beta;
    out_tail[0] = (float)eps;
    out_tail[1] = (float)beta;
  }
}

// ---------------- K4: the big N^3 cond write (float32) -------------------
// grid (4, 384): a = blockIdx.y, p-quarter = blockIdx.x. block 256.
// Each block: 96 p-rows x 384 n = 9216 float4 stores = 36 iters.
__global__ __launch_bounds__(256) void k_cond(const double* __restrict__ mat,
                                              const int* __restrict__ labels,
                                              const double* __restrict__ sc,
                                              float* __restrict__ out) {
  __shared__ double matA[N];
  __shared__ int labs[N];
  int a = blockIdx.y;
  int pq = blockIdx.x;
  int t = threadIdx.x;
  for (int i = t; i < N; i += 256) {
    matA[i] = mat[(size_t)a * N + i];
    labs[i] = labels[i];
  }
  __syncthreads();
  double eps = sc[0];
  int la = labs[a];
  float4* outv = (float4*)(out + (size_t)a * N2);
  for (int it = 0; it < 36; ++it) {
    int i = it * 256 + t;          // 0..9215
    int p = pq * 96 + (i / 96);
    int n0 = (i % 96) * 4;
    float4 w = make_float4(0.f, 0.f, 0.f, 0.f);
    if ((labs[p] == la) && (p != a)) {
      double mp = matA[p];
      float r[4];
#pragma unroll
      for (int j = 0; j < 4; ++j) {
        int n = n0 + j;
        double d = matA[n] - mp;
        r[j] = ((labs[n] != la) && (d > 0.0) && (d <= eps)) ? 1.0f : 0.0f;
      }
      w = make_float4(r[0], r[1], r[2], r[3]);
    }
    outv[((size_t)p * N + n0) >> 2] = w;
  }
}

// ---------------- K5: an_pairs write (float32) ---------------------------
__global__ __launch_bounds__(256) void k_an(const double* __restrict__ mat,
                                            const int* __restrict__ labels,
                                            const int* __restrict__ hp,
                                            const double* __restrict__ sc,
                                            float* __restrict__ out) {
  int gid = blockIdx.x * 256 + threadIdx.x;   // 144 blocks -> 36864 threads
  int a = gid / 96;
  int b0 = (gid % 96) * 4;
  double beta = sc[1];
  int la = labels[a];
  int hpa = hp[a];
  float r[4];
#pragma unroll
  for (int j = 0; j < 4; ++j) {
    int b = b0 + j;
    bool pm = (a < b) && (labels[b] != la) && (hpa || hp[b]);
    r[j] = (pm && (-mat[(size_t)a * N + b] >= beta)) ? 1.0f : 0.0f;
  }
  *((float4*)(out + N3 + (size_t)gid * 4)) = make_float4(r[0], r[1], r[2], r[3]);
}

extern "C" void kernel_launch(void* const* d_in, const int* in_sizes, int n_in,
                              void* d_out, int out_size, void* d_ws, size_t ws_size,
                              hipStream_t stream) {
  const float* logits = (const float*)d_in[0];
  const int* labels = (const int*)d_in[1];
  float* out = (float*)d_out;
  char* ws = (char*)d_ws;
  double* mat = (double*)(ws + MAT_OFF);
  double* tn  = (double*)(ws + TN_OFF);
  double* tc  = (double*)(ws + TC_OFF);
  double* ans = (double*)(ws + ANS_OFF);
  double* anc = (double*)(ws + ANC_OFF);
  int* hp     = (int*)(ws + HP_OFF);
  double* sc  = (double*)(ws + SC_OFF);
  // fp64 scratch carved out of d_out (227 MB); both regions are fully
  // consumed before k_cond overwrites the entire cond area each launch.
  double* part = (double*)((char*)d_out + PART_BYTE);  // 4.7 MB
  double* xn   = (double*)((char*)d_out + XN_BYTE);    // 3.1 MB

  k_norm<<<dim3(N), dim3(256), 0, stream>>>(logits, xn);
  k_gemm<<<dim3(12, 12, 4), dim3(256), 0, stream>>>(xn, part);
  k_reduce_mat<<<dim3(576), dim3(256), 0, stream>>>(part, mat);
  k_stats<<<dim3(N), dim3(384), 0, stream>>>(mat, labels, tn, tc, ans, anc, hp);
  k_final<<<dim3(1), dim3(512), 0, stream>>>(tn, tc, ans, anc, sc,
                                             out + N3 + N2);
  k_cond<<<dim3(4, N), dim3(256), 0, stream>>>(mat, labels, sc, out);
  k_an<<<dim3(144), dim3(256), 0, stream>>>(mat, labels, hp, sc, out);
}

// Round 4
// 59.191 us; speedup vs baseline: 1.3315x; 1.3315x over previous
//
#include <hip/hip_runtime.h>
#include <stdint.h>

#define N 384
#define D 1024
#define N2 (N * N)            // 147456
static constexpr size_t N3 = (size_t)N * N2;  // 56623104

// ---- workspace byte offsets (total ~3.56 MB) ----
static constexpr size_t PART_OFF = 0;              // 2*147456*8 = 2359296
static constexpr size_t MAT_OFF  = 2359296;        // 147456*8   = 1179648
static constexpr size_t INVN_OFF = 3538944;        // 384*8
static constexpr size_t TN_OFF   = 3542016;
static constexpr size_t TC_OFF   = 3545088;
static constexpr size_t ANS_OFF  = 3548160;
static constexpr size_t ANC_OFF  = 3551232;
static constexpr size_t HP_OFF   = 3554304;        // 384 ints
static constexpr size_t SC_OFF   = 3555840;        // 2 doubles

static constexpr int GEMM_BLOCKS = 288;            // 12*12*2 (K-split 2)
static constexpr int FILL_BLOCKS = 2048;
static constexpr size_t FILL_F4  = 14192640;       // 56770560/4 booleans

// ---------------- K1: per-row 1/||x|| in fp64 (one wave per row) ---------
__global__ __launch_bounds__(256) void k_invnorm(const float* __restrict__ x,
                                                 double* __restrict__ invn) {
  int w = threadIdx.x >> 6, lane = threadIdx.x & 63;
  int a = blockIdx.x * 4 + w;
  const float4* row = (const float4*)(x + (size_t)a * D);
  double s = 0.0;
#pragma unroll
  for (int j = 0; j < 4; ++j) {
    float4 v = row[lane + 64 * j];
    double dx = v.x, dy = v.y, dz = v.z, dw = v.w;
    s += dx * dx + dy * dy + dz * dz + dw * dw;
  }
#pragma unroll
  for (int m = 32; m; m >>= 1) s += __shfl_xor(s, m, 64);
  if (lane == 0) invn[a] = 1.0 / sqrt(s);
}

// ---------------- K2: mega — fp64 GEMM partials + 227MB zero-fill --------
// blocks [0,288): GEMM tiles (32x32, K-split 2, f32 loads, f64 LDS/acc).
// blocks [288, 2336): grid-stride float4 zero-fill of the boolean output.
__global__ __launch_bounds__(256) void k_mega(const float* __restrict__ x,
                                              const double* __restrict__ invn,
                                              double* __restrict__ part,
                                              float4* __restrict__ outv) {
  __shared__ double As[64][32];
  __shared__ double Bs[64][32];
  int b = blockIdx.x;
  int t = threadIdx.x;
  if (b >= GEMM_BLOCKS) {
    size_t i = (size_t)(b - GEMM_BLOCKS) * 256 + t;
    const size_t stride = (size_t)FILL_BLOCKS * 256;
    float4 z = make_float4(0.f, 0.f, 0.f, 0.f);
    for (; i < FILL_F4; i += stride) outv[i] = z;
    return;
  }
  int bz = b / 144, rem = b % 144;
  int m0 = (rem % 12) * 32, n0 = (rem / 12) * 32, k0 = bz * 512;
  int tm = t & 15, tn = t >> 4;
  double a00 = 0, a01 = 0, a10 = 0, a11 = 0;
  for (int kc = 0; kc < 8; ++kc) {
    int kbase = k0 + kc * 64;
#pragma unroll
    for (int h = 0; h < 2; ++h) {
      int f = t + h * 256;          // 0..511
      int m = f & 31, kq = f >> 5;  // kq 0..15
      float4 va = *(const float4*)(x + (size_t)(m0 + m) * D + kbase + kq * 4);
      As[kq * 4 + 0][m] = (double)va.x; As[kq * 4 + 1][m] = (double)va.y;
      As[kq * 4 + 2][m] = (double)va.z; As[kq * 4 + 3][m] = (double)va.w;
      float4 vb = *(const float4*)(x + (size_t)(n0 + m) * D + kbase + kq * 4);
      Bs[kq * 4 + 0][m] = (double)vb.x; Bs[kq * 4 + 1][m] = (double)vb.y;
      Bs[kq * 4 + 2][m] = (double)vb.z; Bs[kq * 4 + 3][m] = (double)vb.w;
    }
    __syncthreads();
#pragma unroll 8
    for (int k = 0; k < 64; ++k) {
      double ax = As[k][2 * tm], ay = As[k][2 * tm + 1];
      double bx = Bs[k][2 * tn], by = Bs[k][2 * tn + 1];
      a00 = fma(ax, bx, a00);
      a01 = fma(ax, by, a01);
      a10 = fma(ay, bx, a10);
      a11 = fma(ay, by, a11);
    }
    __syncthreads();
  }
  int r0 = m0 + 2 * tm, c0 = n0 + 2 * tn;
  double i0 = invn[r0], i1 = invn[r0 + 1], j0 = invn[c0], j1 = invn[c0 + 1];
  double* o = part + (size_t)bz * N2;
  o[(size_t)r0 * N + c0]           = a00 * (i0 * j0);
  o[(size_t)r0 * N + c0 + 1]       = a01 * (i0 * j1);
  o[(size_t)(r0 + 1) * N + c0]     = a10 * (i1 * j0);
  o[(size_t)(r0 + 1) * N + c0 + 1] = a11 * (i1 * j1);
}

// ---------------- K3: mat row + per-anchor stats (shfl butterflies) ------
__global__ __launch_bounds__(384) void k_stats(const double* __restrict__ part,
                                               const int* __restrict__ labels,
                                               double* __restrict__ mat,
                                               double* __restrict__ tn,
                                               double* __restrict__ tc,
                                               double* __restrict__ ans,
                                               double* __restrict__ anc,
                                               int* __restrict__ hp) {
  __shared__ int labs[N];
  __shared__ int hist[32];
  __shared__ double cw[6][6];
  int a = blockIdx.x, t = threadIdx.x;
  int w = t >> 6, lane = t & 63;
  if (t < 32) hist[t] = 0;
  labs[t] = labels[t];
  __syncthreads();
  atomicAdd(&hist[labs[t] & 31], 1);
  __syncthreads();
  int la = labs[a];
  double m = -(part[(size_t)a * N + t] + part[(size_t)N2 + (size_t)a * N + t]);
  mat[(size_t)a * N + t] = m;
  bool same = (labs[t] == la) && (t != a);
  bool diff = (labs[t] != la);
  bool hpa = hist[la] >= 2;
  bool hpt = hist[labs[t]] >= 2;
  bool anm = (t > a) && diff && (hpa || hpt);

  double q[6];
  q[0] = same ? m : 0.0;
  q[1] = same ? 1.0 : 0.0;
  q[2] = diff ? m : 0.0;
  q[3] = diff ? 1.0 : 0.0;
  q[4] = anm ? m : 0.0;
  q[5] = anm ? 1.0 : 0.0;
#pragma unroll
  for (int i = 0; i < 6; ++i) {
#pragma unroll
    for (int s = 32; s; s >>= 1) q[i] += __shfl_xor(q[i], s, 64);
  }
  if (lane == 0) {
#pragma unroll
    for (int i = 0; i < 6; ++i) cw[w][i] = q[i];
  }
  __syncthreads();
  if (t == 0) {
    double r[6];
#pragma unroll
    for (int i = 0; i < 6; ++i) {
      double s = 0.0;
      for (int ww = 0; ww < 6; ++ww) s += cw[ww][i];
      r[i] = s;
    }
    tn[a]  = r[2] * r[1] - r[0] * r[3];
    tc[a]  = r[1] * r[3];
    ans[a] = r[4];
    anc[a] = r[5];
    hp[a]  = hpa ? 1 : 0;
  }
}

// ---------------- K4: final scalars eps/beta (one wave) ------------------
__global__ __launch_bounds__(64) void k_final(const double* __restrict__ tn,
                                              const double* __restrict__ tc,
                                              const double* __restrict__ ans,
                                              const double* __restrict__ anc,
                                              double* __restrict__ sc,
                                              float* __restrict__ out_tail) {
  int t = threadIdx.x;
  double vtn = 0, vtc = 0, vas = 0, vac = 0;
#pragma unroll
  for (int j = 0; j < 6; ++j) {
    vtn += tn[t + 64 * j];
    vtc += tc[t + 64 * j];
    vas += ans[t + 64 * j];
    vac += anc[t + 64 * j];
  }
#pragma unroll
  for (int s = 32; s; s >>= 1) {
    vtn += __shfl_xor(vtn, s, 64);
    vtc += __shfl_xor(vtc, s, 64);
    vas += __shfl_xor(vas, s, 64);
    vac += __shfl_xor(vac, s, 64);
  }
  if (t == 0) {
    double an_mean = vas / fmax(vac, 1.0);
    double beta = 1.0 + ((-an_mean) - 1.0) / 2.0;
    double em = vtn / fmax(vtc, 1.0);
    double eps = em / 2.0;
    eps = eps < 0.0 ? 0.0 : (eps > 0.5 ? 0.5 : eps);
    sc[0] = eps;
    sc[1] = beta;
    out_tail[0] = (float)eps;
    out_tail[1] = (float)beta;
  }
}

// ---------------- K5: sparse rewrite — same-rows of cond + an rows -------
__global__ __launch_bounds__(256) void k_sparse(const double* __restrict__ mat,
                                                const int* __restrict__ labels,
                                                const int* __restrict__ hp,
                                                const double* __restrict__ sc,
                                                float* __restrict__ out) {
  __shared__ int labs[N];
  __shared__ int hpL[N];
  __shared__ double matA[N];
  __shared__ int list[N];
  __shared__ int cnt;
  int a = blockIdx.x, t = threadIdx.x;
  for (int i = t; i < N; i += 256) {
    labs[i] = labels[i];
    hpL[i] = hp[i];
    matA[i] = mat[(size_t)a * N + i];
  }
  if (t == 0) cnt = 0;
  __syncthreads();
  int la = labs[a];
  for (int i = t; i < N; i += 256) {
    if (labs[i] == la && i != a) list[atomicAdd(&cnt, 1)] = i;
  }
  __syncthreads();
  double eps = sc[0], beta = sc[1];
  int hpa = hpL[a];
  // an row a
  if (t < 96) {
    int b0 = t * 4;
    float r[4];
#pragma unroll
    for (int j = 0; j < 4; ++j) {
      int b = b0 + j;
      bool pm = (a < b) && (labs[b] != la) && (hpa || hpL[b]);
      r[j] = (pm && (-matA[b] >= beta)) ? 1.0f : 0.0f;
    }
    *((float4*)(out + N3 + (size_t)a * N + b0)) = make_float4(r[0], r[1], r[2], r[3]);
  }
  // same rows of cond[a], two rows per iteration (threads 0..191)
  int nc = cnt;
  for (int base = 0; base < nc; base += 2) {
    int rr = base + (t / 96);
    if (t < 192 && rr < nc) {
      int p = list[rr];
      double mp = matA[p];
      int n0 = (t % 96) * 4;
      float r[4];
#pragma unroll
      for (int j = 0; j < 4; ++j) {
        int n = n0 + j;
        double d = matA[n] - mp;
        r[j] = ((labs[n] != la) && (d > 0.0) && (d <= eps)) ? 1.0f : 0.0f;
      }
      *((float4*)(out + (size_t)a * N2 + (size_t)p * N + n0)) =
          make_float4(r[0], r[1], r[2], r[3]);
    }
  }
}

extern "C" void kernel_launch(void* const* d_in, const int* in_sizes, int n_in,
                              void* d_out, int out_size, void* d_ws, size_t ws_size,
                              hipStream_t stream) {
  const float* logits = (const float*)d_in[0];
  const int* labels = (const int*)d_in[1];
  float* out = (float*)d_out;
  char* ws = (char*)d_ws;
  double* part = (double*)(ws + PART_OFF);
  double* mat  = (double*)(ws + MAT_OFF);
  double* invn = (double*)(ws + INVN_OFF);
  double* tn   = (double*)(ws + TN_OFF);
  double* tc   = (double*)(ws + TC_OFF);
  double* ans  = (double*)(ws + ANS_OFF);
  double* anc  = (double*)(ws + ANC_OFF);
  int* hp      = (int*)(ws + HP_OFF);
  double* sc   = (double*)(ws + SC_OFF);

  k_invnorm<<<dim3(96), dim3(256), 0, stream>>>(logits, invn);
  k_mega<<<dim3(GEMM_BLOCKS + FILL_BLOCKS), dim3(256), 0, stream>>>(
      logits, invn, part, (float4*)out);
  k_stats<<<dim3(N), dim3(384), 0, stream>>>(part, labels, mat, tn, tc, ans,
                                             anc, hp);
  k_final<<<dim3(1), dim3(64), 0, stream>>>(tn, tc, ans, anc, sc,
                                            out + N3 + N2);
  k_sparse<<<dim3(N), dim3(256), 0, stream>>>(mat, labels, hp, sc, out);
}